// Round 6
// baseline (302.245 us; speedup 1.0000x reference)
//
#include <hip/hip_runtime.h>

// GQA causal+segment-masked flash attention. fp32 in/out.
// B=2, T=2048, NQ=32 (8 kv heads x 4), D=128.
// R6: M=32 Q-rows per wave (two 16-row groups share one K/V fragment read),
// block covers 128 rows. Unnormalized exp2 accumulation (R5), prep'd split-bf16
// K + V^T tiles in ws (R3/R4), wave-uniform causal group skip.

typedef __bf16 bf16x8 __attribute__((ext_vector_type(8)));
typedef float f32x4 __attribute__((ext_vector_type(4)));

#define B_   2
#define T_   2048
#define NQ_  32
#define NKV_ 8
#define D_   128

#define PSTR 40
#define MASKV (-3.0e38f)
#define LOG2E 1.44269504f
#define TILE_US 12288          // ushorts per 32-col KV tile block in ws (24KB)
#define WS_TILES_BYTES ((size_t)B_ * NKV_ * (T_ / 32) * TILE_US * 2)   // 25165824
#define WS_NEED (WS_TILES_BYTES + (size_t)B_ * T_ * 4)

static __device__ __forceinline__ unsigned short f2bf(float x) {
    union { float f; unsigned int u; } c; c.f = x;
    unsigned int r = c.u + 0x7fffu + ((c.u >> 16) & 1u);
    return (unsigned short)(r >> 16);
}
static __device__ __forceinline__ float bf2f(unsigned short h) {
    union { unsigned int u; float f; } c; c.u = (unsigned int)h << 16; return c.f;
}

union U8 { unsigned short us[8]; bf16x8 v; };

static __device__ __forceinline__ void dma16(const unsigned short* g, unsigned short* l) {
    __builtin_amdgcn_global_load_lds(
        (const __attribute__((address_space(1))) unsigned int*)g,
        (__attribute__((address_space(3))) unsigned int*)l, 16, 0, 0);
}

// ---------------- prep 1: fp32 K/V -> swizzled bf16 ws tiles ----------------
__global__ __launch_bounds__(256)
void prep(const float* __restrict__ kg, const float* __restrict__ vg,
          unsigned short* __restrict__ ws)
{
    const int tid = threadIdx.x;
    const int st  = blockIdx.x;    // 32-col KV tile index, 0..63
    const int kvh = blockIdx.y;
    const int b   = blockIdx.z;
    unsigned short* base = ws + ((size_t)((b * NKV_ + kvh) * (T_ / 32) + st)) * TILE_US;

    #pragma unroll
    for (int it = 0; it < 2; ++it) {
        int task = tid + it * 256;
        int r = task >> 4, c = task & 15;
        const float* kp = kg + (((size_t)(b * T_ + st * 32 + r)) * NKV_ + kvh) * D_ + c * 8;
        U8 hu, lu;
        #pragma unroll
        for (int j = 0; j < 8; ++j) {
            float x = kp[j];
            unsigned short h = f2bf(x);
            hu.us[j] = h;
            lu.us[j] = f2bf(x - bf2f(h));
        }
        int slot = r * 16 + (c ^ (r & 7));
        *(bf16x8*)(base + slot * 8)        = hu.v;
        *(bf16x8*)(base + 4096 + slot * 8) = lu.v;
    }
    #pragma unroll
    for (int it = 0; it < 2; ++it) {
        int task = tid + it * 256;
        int d = task & 127, sc = task >> 7;
        const float* vp = vg + (((size_t)(b * T_ + st * 32 + sc * 8)) * NKV_ + kvh) * D_ + d;
        U8 pk;
        #pragma unroll
        for (int j = 0; j < 8; ++j) pk.us[j] = f2bf(vp[j * (NKV_ * D_)]);
        int slot = d * 4 + (sc ^ (d & 3));
        *(bf16x8*)(base + 8192 + slot * 8) = pk.v;
    }
}

// ---------------- prep 2: per-row segment start indices ----------------
__global__ __launch_bounds__(256)
void prep_sstart(const int* __restrict__ seg, int* __restrict__ sstart)
{
    int idx = blockIdx.x * 256 + threadIdx.x;   // 0 .. B_*T_-1
    int b = idx >> 11, t = idx & (T_ - 1);
    const int* sb = seg + b * T_;
    int target = sb[t];
    int lo = 0, hi = t;
    while (lo < hi) { int mid = (lo + hi) >> 1; if (sb[mid] < target) lo = mid + 1; else hi = mid; }
    sstart[idx] = lo;
}

// ---------------- main attention kernel ----------------
__global__ __launch_bounds__(256)
void attn_fwd(const float* __restrict__ qg,
              const int* __restrict__ sstart,
              const unsigned short* __restrict__ ws,
              float* __restrict__ outg)
{
    __shared__ unsigned short sA[TILE_US];
    __shared__ unsigned short sB[TILE_US];
    __shared__ unsigned short sP[4][2][16 * PSTR];

    const int tid  = threadIdx.x;
    const int wave = tid >> 6;
    const int lane = tid & 63;
    const int qd   = lane >> 4;
    const int ln   = lane & 15;

    const int t0   = ((int)gridDim.x - 1 - (int)blockIdx.x) * 128;  // heavy-first
    const int head = blockIdx.y;
    const int kvh  = head >> 2;
    const int b    = blockIdx.z;

    // ---- preload Q fragments for both row groups (rows t0+g*64+wave*16+ln) ----
    bf16x8 qh[2][4], ql[2][4];
    #pragma unroll
    for (int g = 0; g < 2; ++g) {
        const float* qrow =
            qg + (((size_t)(b * T_ + (t0 + g * 64 + wave * 16 + ln)) * NQ_) + head) * D_;
        #pragma unroll
        for (int c = 0; c < 4; ++c) {
            float4 a  = *(const float4*)(qrow + c * 32 + qd * 8);
            float4 b2 = *(const float4*)(qrow + c * 32 + qd * 8 + 4);
            float xs[8] = {a.x, a.y, a.z, a.w, b2.x, b2.y, b2.z, b2.w};
            U8 hu, lu;
            #pragma unroll
            for (int j = 0; j < 8; ++j) {
                float x = xs[j] * LOG2E;
                unsigned short h = f2bf(x);
                hu.us[j] = h;
                lu.us[j] = f2bf(x - bf2f(h));
            }
            qh[g][c] = hu.v; ql[g][c] = lu.v;
        }
    }

    // ---- per-row segment starts, wave-uniform bounds ----
    int rowstart[2][4], row_min[2], rs_max[2];
    #pragma unroll
    for (int g = 0; g < 2; ++g) {
        int4 rs = *(const int4*)(sstart + b * T_ + t0 + g * 64 + wave * 16 + qd * 4);
        rowstart[g][0] = rs.x; rowstart[g][1] = rs.y;
        rowstart[g][2] = rs.z; rowstart[g][3] = rs.w;
        int m = max(max(rs.x, rs.y), max(rs.z, rs.w));
        m = max(m, __shfl_xor(m, 16));
        m = max(m, __shfl_xor(m, 32));
        rs_max[g]  = m;
        row_min[g] = t0 + g * 64 + wave * 16;
    }

    const int tile0   = sstart[b * T_ + t0] >> 5;       // block-uniform (seg sorted)
    const int n_tiles = t0 / 32 + 4;                    // covers s in [0, t0+127]

    f32x4 O[2][8];
    #pragma unroll
    for (int g = 0; g < 2; ++g)
        #pragma unroll
        for (int i = 0; i < 8; ++i) O[g][i] = (f32x4){0.f, 0.f, 0.f, 0.f};
    float l_lane[2][4] = {{0.f,0.f,0.f,0.f},{0.f,0.f,0.f,0.f}};

    const unsigned short* wsbase =
        ws + ((size_t)((b * NKV_ + kvh) * (T_ / 32))) * TILE_US;

    int koff[4];
    #pragma unroll
    for (int c = 0; c < 4; ++c)
        koff[c] = (ln * 16 + ((4 * c + qd) ^ (ln & 7))) * 8;
    const int vbase = (ln * 4 + (qd ^ (ln & 3))) * 8;

#define STAGE(dst, tl) do {                                                    \
        const unsigned short* _tb = wsbase + (size_t)(tl) * TILE_US;           \
        _Pragma("unroll")                                                      \
        for (int _i = 0; _i < 6; ++_i)                                         \
            dma16(_tb + ((wave * 6 + _i) * 64 + lane) * 8,                     \
                  (dst) + (wave * 6 + _i) * 512);                              \
    } while (0)

#define COMPUTE(BUF, TL) do {                                                  \
        const unsigned short* _Khi = (BUF);                                    \
        const unsigned short* _Klo = (BUF) + 4096;                             \
        const unsigned short* _Vt  = (BUF) + 8192;                             \
        const int _s0 = (TL) * 32;                                             \
        const bool act0 = (_s0 <= row_min[0] + 15);                            \
        const bool act1 = (_s0 <= row_min[1] + 15);                            \
        f32x4 S[2][2];                                                         \
        S[0][0]=(f32x4){0.f,0.f,0.f,0.f}; S[0][1]=(f32x4){0.f,0.f,0.f,0.f};    \
        S[1][0]=(f32x4){0.f,0.f,0.f,0.f}; S[1][1]=(f32x4){0.f,0.f,0.f,0.f};    \
        _Pragma("unroll")                                                      \
        for (int c = 0; c < 4; ++c) {                                          \
            bf16x8 kh0 = *(const bf16x8*)(_Khi + koff[c]);                     \
            bf16x8 kh1 = *(const bf16x8*)(_Khi + koff[c] + 2048);              \
            bf16x8 kl0 = *(const bf16x8*)(_Klo + koff[c]);                     \
            bf16x8 kl1 = *(const bf16x8*)(_Klo + koff[c] + 2048);              \
            if (act0) {                                                        \
                S[0][0] = __builtin_amdgcn_mfma_f32_16x16x32_bf16(qh[0][c], kh0, S[0][0],0,0,0); \
                S[0][1] = __builtin_amdgcn_mfma_f32_16x16x32_bf16(qh[0][c], kh1, S[0][1],0,0,0); \
                S[0][0] = __builtin_amdgcn_mfma_f32_16x16x32_bf16(qh[0][c], kl0, S[0][0],0,0,0); \
                S[0][1] = __builtin_amdgcn_mfma_f32_16x16x32_bf16(qh[0][c], kl1, S[0][1],0,0,0); \
                S[0][0] = __builtin_amdgcn_mfma_f32_16x16x32_bf16(ql[0][c], kh0, S[0][0],0,0,0); \
                S[0][1] = __builtin_amdgcn_mfma_f32_16x16x32_bf16(ql[0][c], kh1, S[0][1],0,0,0); \
            }                                                                  \
            if (act1) {                                                        \
                S[1][0] = __builtin_amdgcn_mfma_f32_16x16x32_bf16(qh[1][c], kh0, S[1][0],0,0,0); \
                S[1][1] = __builtin_amdgcn_mfma_f32_16x16x32_bf16(qh[1][c], kh1, S[1][1],0,0,0); \
                S[1][0] = __builtin_amdgcn_mfma_f32_16x16x32_bf16(qh[1][c], kl0, S[1][0],0,0,0); \
                S[1][1] = __builtin_amdgcn_mfma_f32_16x16x32_bf16(qh[1][c], kl1, S[1][1],0,0,0); \
                S[1][0] = __builtin_amdgcn_mfma_f32_16x16x32_bf16(ql[1][c], kh0, S[1][0],0,0,0); \
                S[1][1] = __builtin_amdgcn_mfma_f32_16x16x32_bf16(ql[1][c], kh1, S[1][1],0,0,0); \
            }                                                                  \
        }                                                                      \
        bf16x8 bv[8];                                                          \
        _Pragma("unroll")                                                      \
        for (int sub = 0; sub < 8; ++sub)                                      \
            bv[sub] = *(const bf16x8*)(_Vt + vbase + sub * 512);               \
        _Pragma("unroll")                                                      \
        for (int g = 0; g < 2; ++g) {                                          \
            if (!(g ? act1 : act0)) continue;                                  \
            float p0[4], p1[4];                                                \
            if (_s0 >= rs_max[g] && _s0 + 31 <= row_min[g]) {                  \
                _Pragma("unroll")                                              \
                for (int r = 0; r < 4; ++r) {                                  \
                    p0[r] = exp2f(S[g][0][r]);                                 \
                    p1[r] = exp2f(S[g][1][r]);                                 \
                }                                                              \
            } else {                                                           \
                _Pragma("unroll")                                              \
                for (int r = 0; r < 4; ++r) {                                  \
                    int tr = row_min[g] + qd * 4 + r;                          \
                    int sc0 = _s0 + ln, sc1 = _s0 + 16 + ln;                   \
                    float sv0 = (sc0 >= rowstart[g][r] && sc0 <= tr) ? S[g][0][r] : MASKV; \
                    float sv1 = (sc1 >= rowstart[g][r] && sc1 <= tr) ? S[g][1][r] : MASKV; \
                    p0[r] = exp2f(sv0);                                        \
                    p1[r] = exp2f(sv1);                                        \
                }                                                              \
            }                                                                  \
            _Pragma("unroll")                                                  \
            for (int r = 0; r < 4; ++r) l_lane[g][r] += p0[r] + p1[r];         \
            unsigned short* pw = sP[wave][g] + (qd * 4) * PSTR + ln;           \
            _Pragma("unroll")                                                  \
            for (int r = 0; r < 4; ++r) {                                      \
                pw[r * PSTR]      = f2bf(p0[r]);                               \
                pw[r * PSTR + 16] = f2bf(p1[r]);                               \
            }                                                                  \
        }                                                                      \
        asm volatile("s_waitcnt lgkmcnt(0)" ::: "memory");                     \
        if (act0) {                                                            \
            bf16x8 pa = *(const bf16x8*)(sP[wave][0] + ln * PSTR + qd * 8);    \
            _Pragma("unroll")                                                  \
            for (int sub = 0; sub < 8; ++sub)                                  \
                O[0][sub] = __builtin_amdgcn_mfma_f32_16x16x32_bf16(pa, bv[sub], O[0][sub],0,0,0); \
        }                                                                      \
        if (act1) {                                                            \
            bf16x8 pa = *(const bf16x8*)(sP[wave][1] + ln * PSTR + qd * 8);    \
            _Pragma("unroll")                                                  \
            for (int sub = 0; sub < 8; ++sub)                                  \
                O[1][sub] = __builtin_amdgcn_mfma_f32_16x16x32_bf16(pa, bv[sub], O[1][sub],0,0,0); \
        }                                                                      \
    } while (0)

    int t = tile0;
    STAGE(sA, t);
    __syncthreads();                       // drains DMA into sA
    while (t + 1 < n_tiles) {
        STAGE(sB, t + 1);                  // prefetch under compute(sA)
        COMPUTE(sA, t);
        __syncthreads();                   // drains DMA(sB); sA reads done
        if (t + 2 < n_tiles) STAGE(sA, t + 2);
        COMPUTE(sB, t + 1);
        __syncthreads();                   // drains DMA(sA); sB reads done
        t += 2;
    }
    if (t < n_tiles) COMPUTE(sA, t);

#undef STAGE
#undef COMPUTE

    // ---- epilogue: reduce l across the 16 row-lanes, normalize, store ----
    #pragma unroll
    for (int g = 0; g < 2; ++g) {
        float inv[4];
        #pragma unroll
        for (int r = 0; r < 4; ++r) {
            float l = l_lane[g][r];
            l += __shfl_xor(l, 1);
            l += __shfl_xor(l, 2);
            l += __shfl_xor(l, 4);
            l += __shfl_xor(l, 8);
            inv[r] = 1.0f / l;
        }
        #pragma unroll
        for (int sub = 0; sub < 8; ++sub) {
            #pragma unroll
            for (int r = 0; r < 4; ++r) {
                const int tr = t0 + g * 64 + wave * 16 + qd * 4 + r;
                outg[(((size_t)(b * T_ + tr) * NQ_) + head) * D_ + sub * 16 + ln] =
                    O[g][sub][r] * inv[r];
            }
        }
    }
}

// ---------------- fallback (no-ws path, known-good R2 structure) ----------------
#define KSTR 136
#define VSTR 40
__global__ __launch_bounds__(256)
void attn_fwd_fb(const float* __restrict__ qg,
                 const float* __restrict__ kg,
                 const float* __restrict__ vg,
                 const int* __restrict__ seg,
                 float* __restrict__ outg)
{
    __shared__ unsigned short sKh[32 * KSTR];
    __shared__ unsigned short sKl[32 * KSTR];
    __shared__ unsigned short sVt[128 * VSTR];
    __shared__ unsigned short sP[4][16 * PSTR];

    const int tid  = threadIdx.x;
    const int wave = tid >> 6;
    const int lane = tid & 63;
    const int qd   = lane >> 4;
    const int ln   = lane & 15;
    const int t0   = ((int)gridDim.x - 1 - (int)blockIdx.x) * 64;
    const int head = blockIdx.y;
    const int kvh  = head >> 2;
    const int b    = blockIdx.z;

    bf16x8 qh[4], ql[4];
    {
        const float* qrow =
            qg + (((size_t)(b * T_ + (t0 + wave * 16 + ln)) * NQ_) + head) * D_;
        #pragma unroll
        for (int c = 0; c < 4; ++c) {
            float4 a  = *(const float4*)(qrow + c * 32 + qd * 8);
            float4 b2 = *(const float4*)(qrow + c * 32 + qd * 8 + 4);
            float xs[8] = {a.x, a.y, a.z, a.w, b2.x, b2.y, b2.z, b2.w};
            U8 hu, lu;
            #pragma unroll
            for (int j = 0; j < 8; ++j) {
                unsigned short h = f2bf(xs[j]);
                hu.us[j] = h;
                lu.us[j] = f2bf(xs[j] - bf2f(h));
            }
            qh[c] = hu.v; ql[c] = lu.v;
        }
    }
    const int* sb = seg + (size_t)b * T_;
    int qseg[4];
    #pragma unroll
    for (int r = 0; r < 4; ++r) qseg[r] = sb[t0 + wave * 16 + qd * 4 + r];
    int tile0;
    {
        int target = sb[t0];
        int lo = 0, hi = t0;
        while (lo < hi) { int mid = (lo + hi) >> 1; if (sb[mid] < target) lo = mid + 1; else hi = mid; }
        tile0 = lo >> 5;
    }
    f32x4 O[8];
    #pragma unroll
    for (int i = 0; i < 8; ++i) O[i] = (f32x4){0.f, 0.f, 0.f, 0.f};
    float m_prev[4], l_lane[4];
    #pragma unroll
    for (int r = 0; r < 4; ++r) { m_prev[r] = MASKV; l_lane[r] = 0.f; }
    const int n_tiles = t0 / 32 + 2;

    for (int tile = tile0; tile < n_tiles; ++tile) {
        const int s0 = tile * 32;
        __syncthreads();
        #pragma unroll
        for (int it = 0; it < 2; ++it) {
            int task = tid + it * 256;
            int r = task >> 4, d = (task & 15) * 8;
            const float* kp = kg + (((size_t)(b * T_ + s0 + r) * NKV_) + kvh) * D_ + d;
            float4 a  = *(const float4*)(kp);
            float4 b2 = *(const float4*)(kp + 4);
            float xs[8] = {a.x, a.y, a.z, a.w, b2.x, b2.y, b2.z, b2.w};
            U8 hu, lu;
            #pragma unroll
            for (int j = 0; j < 8; ++j) {
                unsigned short h = f2bf(xs[j]);
                hu.us[j] = h;
                lu.us[j] = f2bf(xs[j] - bf2f(h));
            }
            *(bf16x8*)(sKh + r * KSTR + d) = hu.v;
            *(bf16x8*)(sKl + r * KSTR + d) = lu.v;
        }
        #pragma unroll
        for (int it = 0; it < 2; ++it) {
            int task = tid + it * 256;
            int d = task & 127, sg = task >> 7;
            const float* vp = vg + (((size_t)(b * T_ + s0 + sg * 8) * NKV_) + kvh) * D_ + d;
            U8 pk;
            #pragma unroll
            for (int j = 0; j < 8; ++j) pk.us[j] = f2bf(vp[j * (NKV_ * D_)]);
            *(bf16x8*)(sVt + d * VSTR + sg * 8) = pk.v;
        }
        __syncthreads();

        f32x4 S0 = {0.f,0.f,0.f,0.f}, S1 = {0.f,0.f,0.f,0.f};
        #pragma unroll
        for (int c = 0; c < 4; ++c) {
            bf16x8 kh0 = *(const bf16x8*)(sKh + ln * KSTR + c * 32 + qd * 8);
            bf16x8 kh1 = *(const bf16x8*)(sKh + (16 + ln) * KSTR + c * 32 + qd * 8);
            bf16x8 kl0 = *(const bf16x8*)(sKl + ln * KSTR + c * 32 + qd * 8);
            bf16x8 kl1 = *(const bf16x8*)(sKl + (16 + ln) * KSTR + c * 32 + qd * 8);
            S0 = __builtin_amdgcn_mfma_f32_16x16x32_bf16(qh[c], kh0, S0, 0, 0, 0);
            S1 = __builtin_amdgcn_mfma_f32_16x16x32_bf16(qh[c], kh1, S1, 0, 0, 0);
            S0 = __builtin_amdgcn_mfma_f32_16x16x32_bf16(qh[c], kl0, S0, 0, 0, 0);
            S1 = __builtin_amdgcn_mfma_f32_16x16x32_bf16(qh[c], kl1, S1, 0, 0, 0);
            S0 = __builtin_amdgcn_mfma_f32_16x16x32_bf16(ql[c], kh0, S0, 0, 0, 0);
            S1 = __builtin_amdgcn_mfma_f32_16x16x32_bf16(ql[c], kh1, S1, 0, 0, 0);
        }
        const int ks0 = sb[s0 + ln];
        const int ks1 = sb[s0 + 16 + ln];
        float p0[4], p1[4], alpha[4];
        #pragma unroll
        for (int r = 0; r < 4; ++r) {
            const int trow = t0 + wave * 16 + qd * 4 + r;
            float s0v = ((s0 + ln <= trow) && (ks0 == qseg[r])) ? S0[r] : MASKV;
            float s1v = ((s0 + 16 + ln <= trow) && (ks1 == qseg[r])) ? S1[r] : MASKV;
            float mx = fmaxf(s0v, s1v);
            mx = fmaxf(mx, __shfl_xor(mx, 1));
            mx = fmaxf(mx, __shfl_xor(mx, 2));
            mx = fmaxf(mx, __shfl_xor(mx, 4));
            mx = fmaxf(mx, __shfl_xor(mx, 8));
            const float mn = fmaxf(m_prev[r], mx);
            alpha[r] = __expf(m_prev[r] - mn);
            p0[r] = __expf(s0v - mn);
            p1[r] = __expf(s1v - mn);
            l_lane[r] = alpha[r] * l_lane[r] + p0[r] + p1[r];
            m_prev[r] = mn;
        }
        #pragma unroll
        for (int i = 0; i < 8; ++i) {
            O[i][0] *= alpha[0]; O[i][1] *= alpha[1];
            O[i][2] *= alpha[2]; O[i][3] *= alpha[3];
        }
        {
            unsigned short* pw = sP[wave] + (qd * 4) * PSTR + ln;
            #pragma unroll
            for (int r = 0; r < 4; ++r) {
                pw[r * PSTR]      = f2bf(p0[r]);
                pw[r * PSTR + 16] = f2bf(p1[r]);
            }
        }
        asm volatile("s_waitcnt lgkmcnt(0)" ::: "memory");
        bf16x8 pa = *(const bf16x8*)(sP[wave] + ln * PSTR + qd * 8);
        #pragma unroll
        for (int sub = 0; sub < 8; ++sub) {
            bf16x8 bv = *(const bf16x8*)(sVt + (sub * 16 + ln) * VSTR + qd * 8);
            O[sub] = __builtin_amdgcn_mfma_f32_16x16x32_bf16(pa, bv, O[sub], 0, 0, 0);
        }
    }
    float inv[4];
    #pragma unroll
    for (int r = 0; r < 4; ++r) {
        float l = l_lane[r];
        l += __shfl_xor(l, 1);
        l += __shfl_xor(l, 2);
        l += __shfl_xor(l, 4);
        l += __shfl_xor(l, 8);
        inv[r] = 1.0f / l;
    }
    #pragma unroll
    for (int sub = 0; sub < 8; ++sub) {
        #pragma unroll
        for (int r = 0; r < 4; ++r) {
            const int trow = t0 + wave * 16 + qd * 4 + r;
            outg[(((size_t)(b * T_ + trow) * NQ_) + head) * D_ + sub * 16 + ln] =
                O[sub][r] * inv[r];
        }
    }
}

extern "C" void kernel_launch(void* const* d_in, const int* in_sizes, int n_in,
                              void* d_out, int out_size, void* d_ws, size_t ws_size,
                              hipStream_t stream) {
    const float* q  = (const float*)d_in[0];
    const float* k  = (const float*)d_in[1];
    const float* v  = (const float*)d_in[2];
    const int*   sg = (const int*)d_in[3];
    float*       o  = (float*)d_out;
    if (ws_size >= WS_NEED) {
        unsigned short* ws = (unsigned short*)d_ws;
        int* sstart = (int*)((char*)d_ws + WS_TILES_BYTES);
        prep<<<dim3(T_ / 32, NKV_, B_), dim3(256), 0, stream>>>(k, v, ws);
        prep_sstart<<<dim3(B_ * T_ / 256), dim3(256), 0, stream>>>(sg, sstart);
        attn_fwd<<<dim3(T_ / 128, NQ_, B_), dim3(256), 0, stream>>>(q, sstart, ws, o);
    } else {
        attn_fwd_fb<<<dim3(T_ / 64, NQ_, B_), dim3(256), 0, stream>>>(q, k, v, sg, o);
    }
}

// Round 7
// 222.739 us; speedup vs baseline: 1.3569x; 1.3569x over previous
//
#include <hip/hip_runtime.h>

// GQA causal+segment-masked flash attention. fp32 in/out.
// B=2, T=2048, NQ=32 (8 kv heads x 4), D=128.
// R7: R5 structure (64-row blocks). fp16 K + 2-term fp16 Q split for QK
// (16KB tiles -> 4 blocks/CU), bf16 P/V for PV (P unnormalized, needs range).
// Skewed sP layout kills P-write bank conflicts. Unnormalized exp2 accum.

typedef __bf16 bf16x8 __attribute__((ext_vector_type(8)));
typedef _Float16 f16x8 __attribute__((ext_vector_type(8)));
typedef float f32x4 __attribute__((ext_vector_type(4)));

#define B_   2
#define T_   2048
#define NQ_  32
#define NKV_ 8
#define D_   128

#define MASKV (-3.0e38f)
#define LOG2E 1.44269504f
#define TILE_US 8192           // ushorts per 32-col KV tile in ws: 8KB fp16 K + 8KB bf16 Vt
#define WS_TILES_BYTES ((size_t)B_ * NKV_ * (T_ / 32) * TILE_US * 2)   // 16777216
#define WS_NEED (WS_TILES_BYTES + (size_t)B_ * T_ * 4)

static __device__ __forceinline__ unsigned short f2bf(float x) {
    union { float f; unsigned int u; } c; c.f = x;
    unsigned int r = c.u + 0x7fffu + ((c.u >> 16) & 1u);
    return (unsigned short)(r >> 16);
}

union U8  { unsigned short us[8]; bf16x8 v; };
union H8  { _Float16 h[8]; f16x8 v; };

static __device__ __forceinline__ void dma16(const unsigned short* g, unsigned short* l) {
    __builtin_amdgcn_global_load_lds(
        (const __attribute__((address_space(1))) unsigned int*)g,
        (__attribute__((address_space(3))) unsigned int*)l, 16, 0, 0);
}

// ---------------- prep 1: K -> fp16, V^T -> bf16, swizzled ws tiles ----------------
__global__ __launch_bounds__(256)
void prep(const float* __restrict__ kg, const float* __restrict__ vg,
          unsigned short* __restrict__ ws)
{
    const int tid = threadIdx.x;
    const int st  = blockIdx.x;    // 32-col KV tile index
    const int kvh = blockIdx.y;
    const int b   = blockIdx.z;
    unsigned short* base = ws + ((size_t)((b * NKV_ + kvh) * (T_ / 32) + st)) * TILE_US;

    // K: 512 tasks = 32 rows x 16 chunks(8 elems), fp16
    #pragma unroll
    for (int it = 0; it < 2; ++it) {
        int task = tid + it * 256;
        int r = task >> 4, c = task & 15;
        const float* kp = kg + (((size_t)(b * T_ + st * 32 + r)) * NKV_ + kvh) * D_ + c * 8;
        H8 hu;
        #pragma unroll
        for (int j = 0; j < 8; ++j) hu.h[j] = (_Float16)kp[j];
        int slot = r * 16 + (c ^ (r & 7));
        *(f16x8*)(base + slot * 8) = hu.v;
    }
    // V^T: 512 tasks = 128 d x 4 s-chunks(8 s), bf16
    #pragma unroll
    for (int it = 0; it < 2; ++it) {
        int task = tid + it * 256;
        int d = task & 127, sc = task >> 7;
        const float* vp = vg + (((size_t)(b * T_ + st * 32 + sc * 8)) * NKV_ + kvh) * D_ + d;
        U8 pk;
        #pragma unroll
        for (int j = 0; j < 8; ++j) pk.us[j] = f2bf(vp[j * (NKV_ * D_)]);
        int slot = d * 4 + (sc ^ (d & 3));
        *(bf16x8*)(base + 4096 + slot * 8) = pk.v;
    }
}

// ---------------- prep 2: per-row segment start indices ----------------
__global__ __launch_bounds__(256)
void prep_sstart(const int* __restrict__ seg, int* __restrict__ sstart)
{
    int idx = blockIdx.x * 256 + threadIdx.x;
    int b = idx >> 11, t = idx & (T_ - 1);
    const int* sb = seg + b * T_;
    int target = sb[t];
    int lo = 0, hi = t;
    while (lo < hi) { int mid = (lo + hi) >> 1; if (sb[mid] < target) lo = mid + 1; else hi = mid; }
    sstart[idx] = lo;
}

// ---------------- main attention kernel ----------------
__global__ __launch_bounds__(256)
void attn_fwd(const float* __restrict__ qg,
              const int* __restrict__ sstart,
              const unsigned short* __restrict__ ws,
              float* __restrict__ outg)
{
    __shared__ unsigned short sA[TILE_US];
    __shared__ unsigned short sB[TILE_US];
    __shared__ unsigned short sP[4][704];    // skewed layout, conflict-free

    const int tid  = threadIdx.x;
    const int wave = tid >> 6;
    const int lane = tid & 63;
    const int qd   = lane >> 4;
    const int ln   = lane & 15;

    const int t0   = ((int)gridDim.x - 1 - (int)blockIdx.x) * 64;  // heavy-first
    const int head = blockIdx.y;
    const int kvh  = head >> 2;
    const int b    = blockIdx.z;

    // ---- preload Q fragments, scaled by log2(e), fp16 hi/lo split ----
    f16x8 qh[4], ql[4];
    {
        const float* qrow =
            qg + (((size_t)(b * T_ + (t0 + wave * 16 + ln)) * NQ_) + head) * D_;
        #pragma unroll
        for (int c = 0; c < 4; ++c) {
            float4 a  = *(const float4*)(qrow + c * 32 + qd * 8);
            float4 b2 = *(const float4*)(qrow + c * 32 + qd * 8 + 4);
            float xs[8] = {a.x, a.y, a.z, a.w, b2.x, b2.y, b2.z, b2.w};
            H8 hu, lu;
            #pragma unroll
            for (int j = 0; j < 8; ++j) {
                float x = xs[j] * LOG2E;
                _Float16 h = (_Float16)x;
                hu.h[j] = h;
                lu.h[j] = (_Float16)(x - (float)h);
            }
            qh[c] = hu.v; ql[c] = lu.v;
        }
    }

    // ---- per-row segment starts + causal row indices ----
    int rowstart[4], trow[4];
    {
        int4 rs = *(const int4*)(sstart + b * T_ + t0 + wave * 16 + qd * 4);
        rowstart[0] = rs.x; rowstart[1] = rs.y; rowstart[2] = rs.z; rowstart[3] = rs.w;
        #pragma unroll
        for (int r = 0; r < 4; ++r) trow[r] = t0 + wave * 16 + qd * 4 + r;
    }
    int wave_rs_max = max(max(rowstart[0], rowstart[1]), max(rowstart[2], rowstart[3]));
    wave_rs_max = max(wave_rs_max, __shfl_xor(wave_rs_max, 16));
    wave_rs_max = max(wave_rs_max, __shfl_xor(wave_rs_max, 32));
    const int wave_row_min = t0 + wave * 16;

    const int tile0   = sstart[b * T_ + t0] >> 5;       // block-uniform
    const int n_tiles = t0 / 32 + 2;

    f32x4 O[8];
    #pragma unroll
    for (int i = 0; i < 8; ++i) O[i] = (f32x4){0.f, 0.f, 0.f, 0.f};
    float l_lane[4] = {0.f, 0.f, 0.f, 0.f};

    const unsigned short* wsbase =
        ws + ((size_t)((b * NKV_ + kvh) * (T_ / 32))) * TILE_US;

    int koff[4];
    #pragma unroll
    for (int c = 0; c < 4; ++c)
        koff[c] = (ln * 16 + ((4 * c + qd) ^ (ln & 7))) * 8;
    const int vbase = (ln * 4 + (qd ^ (ln & 3))) * 8;
    // skewed sP addresses (write per r: pwr + r*40 [+16]; read: contiguous b128)
    const int pwbase = (qd * 4) * 40 + qd * 16 + ln;
    const int prbase = ln * 40 + (ln >> 2) * 16 + qd * 8;

#define STAGE(dst, tl) do {                                                    \
        const unsigned short* _tb = wsbase + (size_t)(tl) * TILE_US;           \
        _Pragma("unroll")                                                      \
        for (int _i = 0; _i < 4; ++_i)                                         \
            dma16(_tb + ((wave * 4 + _i) * 64 + lane) * 8,                     \
                  (dst) + (wave * 4 + _i) * 512);                              \
    } while (0)

#define COMPUTE(BUF, TL) do {                                                  \
        const unsigned short* _Kf = (BUF);                                     \
        const unsigned short* _Vt = (BUF) + 4096;                              \
        const int _s0 = (TL) * 32;                                             \
        f32x4 S0 = {0.f,0.f,0.f,0.f}, S1 = {0.f,0.f,0.f,0.f};                  \
        _Pragma("unroll")                                                      \
        for (int c = 0; c < 4; ++c) {                                          \
            f16x8 k0 = *(const f16x8*)(_Kf + koff[c]);                         \
            f16x8 k1 = *(const f16x8*)(_Kf + koff[c] + 2048);                  \
            S0 = __builtin_amdgcn_mfma_f32_16x16x32_f16(qh[c], k0, S0,0,0,0);  \
            S1 = __builtin_amdgcn_mfma_f32_16x16x32_f16(qh[c], k1, S1,0,0,0);  \
            S0 = __builtin_amdgcn_mfma_f32_16x16x32_f16(ql[c], k0, S0,0,0,0);  \
            S1 = __builtin_amdgcn_mfma_f32_16x16x32_f16(ql[c], k1, S1,0,0,0);  \
        }                                                                      \
        bf16x8 bv[8];                                                          \
        _Pragma("unroll")                                                      \
        for (int sub = 0; sub < 8; ++sub)                                      \
            bv[sub] = *(const bf16x8*)(_Vt + vbase + sub * 512);               \
        float p0[4], p1[4];                                                    \
        if (_s0 >= wave_rs_max && _s0 + 31 <= wave_row_min) {                  \
            _Pragma("unroll")                                                  \
            for (int r = 0; r < 4; ++r) {                                      \
                p0[r] = exp2f(S0[r]);                                          \
                p1[r] = exp2f(S1[r]);                                          \
            }                                                                  \
        } else {                                                               \
            _Pragma("unroll")                                                  \
            for (int r = 0; r < 4; ++r) {                                      \
                int sc0 = _s0 + ln, sc1 = _s0 + 16 + ln;                       \
                float sv0 = (sc0 >= rowstart[r] && sc0 <= trow[r]) ? S0[r] : MASKV; \
                float sv1 = (sc1 >= rowstart[r] && sc1 <= trow[r]) ? S1[r] : MASKV; \
                p0[r] = exp2f(sv0);                                            \
                p1[r] = exp2f(sv1);                                            \
            }                                                                  \
        }                                                                      \
        _Pragma("unroll")                                                      \
        for (int r = 0; r < 4; ++r) l_lane[r] += p0[r] + p1[r];                \
        {                                                                      \
            unsigned short* pw = sP[wave] + pwbase;                            \
            _Pragma("unroll")                                                  \
            for (int r = 0; r < 4; ++r) {                                      \
                pw[r * 40]      = f2bf(p0[r]);                                 \
                pw[r * 40 + 16] = f2bf(p1[r]);                                 \
            }                                                                  \
        }                                                                      \
        asm volatile("s_waitcnt lgkmcnt(0)" ::: "memory");                     \
        bf16x8 pa = *(const bf16x8*)(sP[wave] + prbase);                       \
        _Pragma("unroll")                                                      \
        for (int sub = 0; sub < 8; ++sub)                                      \
            O[sub] = __builtin_amdgcn_mfma_f32_16x16x32_bf16(pa, bv[sub], O[sub],0,0,0); \
    } while (0)

    int t = tile0;
    STAGE(sA, t);
    __syncthreads();                       // drains DMA into sA
    while (t + 1 < n_tiles) {
        STAGE(sB, t + 1);                  // prefetch under compute(sA)
        COMPUTE(sA, t);
        __syncthreads();                   // drains DMA(sB); sA reads done
        if (t + 2 < n_tiles) STAGE(sA, t + 2);
        COMPUTE(sB, t + 1);
        __syncthreads();                   // drains DMA(sA); sB reads done
        t += 2;
    }
    if (t < n_tiles) COMPUTE(sA, t);

#undef STAGE
#undef COMPUTE

    // ---- epilogue: reduce l across the 16 row-lanes, normalize, store ----
    float inv[4];
    #pragma unroll
    for (int r = 0; r < 4; ++r) {
        float l = l_lane[r];
        l += __shfl_xor(l, 1);
        l += __shfl_xor(l, 2);
        l += __shfl_xor(l, 4);
        l += __shfl_xor(l, 8);
        inv[r] = 1.0f / l;
    }
    #pragma unroll
    for (int sub = 0; sub < 8; ++sub) {
        #pragma unroll
        for (int r = 0; r < 4; ++r) {
            outg[(((size_t)(b * T_ + trow[r]) * NQ_) + head) * D_ + sub * 16 + ln] =
                O[sub][r] * inv[r];
        }
    }
}

// ---------------- fallback (no-ws path) ----------------
#define KSTR 136
#define VSTR 40
#define PSTR 40
static __device__ __forceinline__ float bf2f(unsigned short h) {
    union { unsigned int u; float f; } c; c.u = (unsigned int)h << 16; return c.f;
}
__global__ __launch_bounds__(256)
void attn_fwd_fb(const float* __restrict__ qg,
                 const float* __restrict__ kg,
                 const float* __restrict__ vg,
                 const int* __restrict__ seg,
                 float* __restrict__ outg)
{
    __shared__ unsigned short sKh[32 * KSTR];
    __shared__ unsigned short sKl[32 * KSTR];
    __shared__ unsigned short sVt[128 * VSTR];
    __shared__ unsigned short sP[4][16 * PSTR];

    const int tid  = threadIdx.x;
    const int wave = tid >> 6;
    const int lane = tid & 63;
    const int qd   = lane >> 4;
    const int ln   = lane & 15;
    const int t0   = ((int)gridDim.x - 1 - (int)blockIdx.x) * 64;
    const int head = blockIdx.y;
    const int kvh  = head >> 2;
    const int b    = blockIdx.z;

    bf16x8 qh[4], ql[4];
    {
        const float* qrow =
            qg + (((size_t)(b * T_ + (t0 + wave * 16 + ln)) * NQ_) + head) * D_;
        #pragma unroll
        for (int c = 0; c < 4; ++c) {
            float4 a  = *(const float4*)(qrow + c * 32 + qd * 8);
            float4 b2 = *(const float4*)(qrow + c * 32 + qd * 8 + 4);
            float xs[8] = {a.x, a.y, a.z, a.w, b2.x, b2.y, b2.z, b2.w};
            U8 hu, lu;
            #pragma unroll
            for (int j = 0; j < 8; ++j) {
                unsigned short h = f2bf(xs[j]);
                hu.us[j] = h;
                lu.us[j] = f2bf(xs[j] - bf2f(h));
            }
            qh[c] = hu.v; ql[c] = lu.v;
        }
    }
    const int* sb = seg + (size_t)b * T_;
    int qseg[4];
    #pragma unroll
    for (int r = 0; r < 4; ++r) qseg[r] = sb[t0 + wave * 16 + qd * 4 + r];
    int tile0;
    {
        int target = sb[t0];
        int lo = 0, hi = t0;
        while (lo < hi) { int mid = (lo + hi) >> 1; if (sb[mid] < target) lo = mid + 1; else hi = mid; }
        tile0 = lo >> 5;
    }
    f32x4 O[8];
    #pragma unroll
    for (int i = 0; i < 8; ++i) O[i] = (f32x4){0.f, 0.f, 0.f, 0.f};
    float m_prev[4], l_lane[4];
    #pragma unroll
    for (int r = 0; r < 4; ++r) { m_prev[r] = MASKV; l_lane[r] = 0.f; }
    const int n_tiles = t0 / 32 + 2;

    for (int tile = tile0; tile < n_tiles; ++tile) {
        const int s0 = tile * 32;
        __syncthreads();
        #pragma unroll
        for (int it = 0; it < 2; ++it) {
            int task = tid + it * 256;
            int r = task >> 4, d = (task & 15) * 8;
            const float* kp = kg + (((size_t)(b * T_ + s0 + r) * NKV_) + kvh) * D_ + d;
            float4 a  = *(const float4*)(kp);
            float4 b2 = *(const float4*)(kp + 4);
            float xs[8] = {a.x, a.y, a.z, a.w, b2.x, b2.y, b2.z, b2.w};
            U8 hu, lu;
            #pragma unroll
            for (int j = 0; j < 8; ++j) {
                unsigned short h = f2bf(xs[j]);
                hu.us[j] = h;
                lu.us[j] = f2bf(xs[j] - bf2f(h));
            }
            *(bf16x8*)(sKh + r * KSTR + d) = hu.v;
            *(bf16x8*)(sKl + r * KSTR + d) = lu.v;
        }
        #pragma unroll
        for (int it = 0; it < 2; ++it) {
            int task = tid + it * 256;
            int d = task & 127, sg = task >> 7;
            const float* vp = vg + (((size_t)(b * T_ + s0 + sg * 8) * NKV_) + kvh) * D_ + d;
            U8 pk;
            #pragma unroll
            for (int j = 0; j < 8; ++j) pk.us[j] = f2bf(vp[j * (NKV_ * D_)]);
            *(bf16x8*)(sVt + d * VSTR + sg * 8) = pk.v;
        }
        __syncthreads();

        f32x4 S0 = {0.f,0.f,0.f,0.f}, S1 = {0.f,0.f,0.f,0.f};
        #pragma unroll
        for (int c = 0; c < 4; ++c) {
            bf16x8 kh0 = *(const bf16x8*)(sKh + ln * KSTR + c * 32 + qd * 8);
            bf16x8 kh1 = *(const bf16x8*)(sKh + (16 + ln) * KSTR + c * 32 + qd * 8);
            bf16x8 kl0 = *(const bf16x8*)(sKl + ln * KSTR + c * 32 + qd * 8);
            bf16x8 kl1 = *(const bf16x8*)(sKl + (16 + ln) * KSTR + c * 32 + qd * 8);
            S0 = __builtin_amdgcn_mfma_f32_16x16x32_bf16(qh[c], kh0, S0, 0, 0, 0);
            S1 = __builtin_amdgcn_mfma_f32_16x16x32_bf16(qh[c], kh1, S1, 0, 0, 0);
            S0 = __builtin_amdgcn_mfma_f32_16x16x32_bf16(qh[c], kl0, S0, 0, 0, 0);
            S1 = __builtin_amdgcn_mfma_f32_16x16x32_bf16(qh[c], kl1, S1, 0, 0, 0);
            S0 = __builtin_amdgcn_mfma_f32_16x16x32_bf16(ql[c], kh0, S0, 0, 0, 0);
            S1 = __builtin_amdgcn_mfma_f32_16x16x32_bf16(ql[c], kh1, S1, 0, 0, 0);
        }
        const int ks0 = sb[s0 + ln];
        const int ks1 = sb[s0 + 16 + ln];
        float p0[4], p1[4], alpha[4];
        #pragma unroll
        for (int r = 0; r < 4; ++r) {
            const int trow = t0 + wave * 16 + qd * 4 + r;
            float s0v = ((s0 + ln <= trow) && (ks0 == qseg[r])) ? S0[r] : MASKV;
            float s1v = ((s0 + 16 + ln <= trow) && (ks1 == qseg[r])) ? S1[r] : MASKV;
            float mx = fmaxf(s0v, s1v);
            mx = fmaxf(mx, __shfl_xor(mx, 1));
            mx = fmaxf(mx, __shfl_xor(mx, 2));
            mx = fmaxf(mx, __shfl_xor(mx, 4));
            mx = fmaxf(mx, __shfl_xor(mx, 8));
            const float mn = fmaxf(m_prev[r], mx);
            alpha[r] = __expf(m_prev[r] - mn);
            p0[r] = __expf(s0v - mn);
            p1[r] = __expf(s1v - mn);
            l_lane[r] = alpha[r] * l_lane[r] + p0[r] + p1[r];
            m_prev[r] = mn;
        }
        #pragma unroll
        for (int i = 0; i < 8; ++i) {
            O[i][0] *= alpha[0]; O[i][1] *= alpha[1];
            O[i][2] *= alpha[2]; O[i][3] *= alpha[3];
        }
        {
            unsigned short* pw = sP[wave] + (qd * 4) * PSTR + ln;
            #pragma unroll
            for (int r = 0; r < 4; ++r) {
                pw[r * PSTR]      = f2bf(p0[r]);
                pw[r * PSTR + 16] = f2bf(p1[r]);
            }
        }
        asm volatile("s_waitcnt lgkmcnt(0)" ::: "memory");
        bf16x8 pa = *(const bf16x8*)(sP[wave] + ln * PSTR + qd * 8);
        #pragma unroll
        for (int sub = 0; sub < 8; ++sub) {
            bf16x8 bv = *(const bf16x8*)(sVt + (sub * 16 + ln) * VSTR + qd * 8);
            O[sub] = __builtin_amdgcn_mfma_f32_16x16x32_bf16(pa, bv, O[sub], 0, 0, 0);
        }
    }
    float inv[4];
    #pragma unroll
    for (int r = 0; r < 4; ++r) {
        float l = l_lane[r];
        l += __shfl_xor(l, 1);
        l += __shfl_xor(l, 2);
        l += __shfl_xor(l, 4);
        l += __shfl_xor(l, 8);
        inv[r] = 1.0f / l;
    }
    #pragma unroll
    for (int sub = 0; sub < 8; ++sub) {
        #pragma unroll
        for (int r = 0; r < 4; ++r) {
            const int trow = t0 + wave * 16 + qd * 4 + r;
            outg[(((size_t)(b * T_ + trow) * NQ_) + head) * D_ + sub * 16 + ln] =
                O[sub][r] * inv[r];
        }
    }
}

extern "C" void kernel_launch(void* const* d_in, const int* in_sizes, int n_in,
                              void* d_out, int out_size, void* d_ws, size_t ws_size,
                              hipStream_t stream) {
    const float* q  = (const float*)d_in[0];
    const float* k  = (const float*)d_in[1];
    const float* v  = (const float*)d_in[2];
    const int*   sg = (const int*)d_in[3];
    float*       o  = (float*)d_out;
    if (ws_size >= WS_NEED) {
        unsigned short* ws = (unsigned short*)d_ws;
        int* sstart = (int*)((char*)d_ws + WS_TILES_BYTES);
        prep<<<dim3(T_ / 32, NKV_, B_), dim3(256), 0, stream>>>(k, v, ws);
        prep_sstart<<<dim3(B_ * T_ / 256), dim3(256), 0, stream>>>(sg, sstart);
        attn_fwd<<<dim3(T_ / 64, NQ_, B_), dim3(256), 0, stream>>>(q, sstart, ws, o);
    } else {
        attn_fwd_fb<<<dim3(T_ / 64, NQ_, B_), dim3(256), 0, stream>>>(q, k, v, sg, o);
    }
}